// Round 6
// baseline (58.098 us; speedup 1.0000x reference)
//
#include <hip/hip_runtime.h>

// Problem constants (fixed by setup_inputs)
#define B 16
#define L 1024
#define D 512
#define T 8192             // mel_max_length
#define D4 (D / 4)         // 128 float4 per row
#define ROWS 64            // output rows per block
#define NBLK (B * T / ROWS)  // 2048 blocks = 8 blocks/CU on 256 CUs

typedef float f4 __attribute__((ext_vector_type(4)));
typedef int   i4 __attribute__((ext_vector_type(4)));

// Single fused kernel. Block = 256 threads, owns 64 contiguous output rows of
// one batch. Prologue: int4-load the batch's 4KB dur row (L2-hot; 128 blocks
// per batch share it), block-wide inclusive scan -> LDS csum[1024]. Wave 0
// binary-searches the 64 row indices in LDS (lane-parallel). Copy phase:
// regular x loads (L1/L2 dedup across adjacent rows), non-temporal stores
// (268MB stream bypasses L2). XCD-chunked swizzle: each XCD owns 2 batches.
__global__ __launch_bounds__(256) void lr_one(const float* __restrict__ x,
                                              const int* __restrict__ dur,
                                              float* __restrict__ out) {
    const int tid  = threadIdx.x;
    const int lane = tid & 63;
    const int wid  = tid >> 6;           // 4 waves
    const int sub     = tid >> 7;        // 0/1 row-group
    const int lane128 = tid & 127;       // float4 column

    __shared__ int cs[L];                // csum
    __shared__ int wsum[4];
    __shared__ int idxl[ROWS];

    const int bid = blockIdx.x;
    const int swz = (bid & 7) * (NBLK / 8) + (bid >> 3);   // XCD-chunked
    const int b   = swz >> 7;            // batch (128 blocks/batch)
    const int t0  = (swz & 127) << 6;    // first output row

    // ---- block-wide inclusive scan of dur[b][0..1024) -> cs ----
    const i4 dv = reinterpret_cast<const i4*>(dur + b * L)[tid];
    const int p0 = dv[0], p1 = p0 + dv[1], p2 = p1 + dv[2], p3 = p2 + dv[3];

    int s = p3;
    #pragma unroll
    for (int off = 1; off < 64; off <<= 1) {
        int n = __shfl_up(s, off, 64);
        if (lane >= off) s += n;
    }
    if (lane == 63) wsum[wid] = s;
    __syncthreads();

    int base = s - p3;                   // exclusive within wave
    #pragma unroll
    for (int w = 0; w < 4; ++w)
        base += (w < wid) ? wsum[w] : 0;

    i4 cv; cv[0] = base + p0; cv[1] = base + p1; cv[2] = base + p2; cv[3] = base + p3;
    reinterpret_cast<i4*>(cs)[tid] = cv;
    __syncthreads();

    // ---- wave 0: upper_bound for each of the 64 rows (lane-parallel) ----
    if (tid < ROWS) {
        const int t = t0 + tid;
        int lo = 0, hi = L;
        while (lo < hi) {
            const int mid = (lo + hi) >> 1;
            if (cs[mid] <= t) lo = mid + 1; else hi = mid;
        }
        idxl[tid] = (lo >= L) ? -1 : lo;   // -1 <=> t >= total  (zero row)
    }
    __syncthreads();

    // ---- copy: 32 rows per 128-thread group, 4-deep unroll for MLP ----
    const f4* __restrict__ xb = reinterpret_cast<const f4*>(x) + (size_t)b * L * D4;
    f4*       __restrict__ ob = reinterpret_cast<f4*>(out)
                                + ((size_t)b * T + t0) * D4;

    for (int i0 = 0; i0 < 32; i0 += 4) {
        int id[4];
        #pragma unroll
        for (int j = 0; j < 4; ++j)
            id[j] = idxl[((i0 + j) << 1) + sub];

        f4 v[4];
        #pragma unroll
        for (int j = 0; j < 4; ++j) {
            if (id[j] >= 0) v[j] = xb[(size_t)id[j] * D4 + lane128];  // wave-uniform
            else            v[j] = (f4)(0.f);
        }
        #pragma unroll
        for (int j = 0; j < 4; ++j) {
            const int r = ((i0 + j) << 1) + sub;
            __builtin_nontemporal_store(v[j], &ob[(size_t)r * D4 + lane128]);
        }
    }
}

extern "C" void kernel_launch(void* const* d_in, const int* in_sizes, int n_in,
                              void* d_out, int out_size, void* d_ws, size_t ws_size,
                              hipStream_t stream) {
    const float* x   = (const float*)d_in[0];
    const int*   dur = (const int*)d_in[1];
    float*       out = (float*)d_out;

    lr_one<<<NBLK, 256, 0, stream>>>(x, dur, out);
}